// Round 1
// baseline (2465.959 us; speedup 1.0000x reference)
//
#include <hip/hip_runtime.h>
#include <hip/hip_bf16.h>

// ---------------- fp32 tiled GEMM: C[M,N] = A[M,K] @ B[K,N] (+ bias[col]) ----
#define BT 64
#define KT 16

__global__ __launch_bounds__(256) void gemm_f32(
    const float* __restrict__ A, const float* __restrict__ B,
    const float* __restrict__ bias, float* __restrict__ C,
    int M, int N, int K) {
  __shared__ float As[KT][BT + 1];  // [k][m], pad to avoid bank conflicts
  __shared__ float Bs[KT][BT];      // [k][n]
  int tid = threadIdx.x;
  int tx = tid & 15, ty = tid >> 4;
  int row0 = blockIdx.y * BT, col0 = blockIdx.x * BT;
  float acc[4][4] = {};
  for (int k0 = 0; k0 < K; k0 += KT) {
#pragma unroll
    for (int l = 0; l < 4; ++l) {
      int idx = tid + l * 256;
      int i = idx >> 4, j = idx & 15;  // i: row in tile, j: k in tile
      int r = row0 + i, kk = k0 + j;
      As[j][i] = (r < M && kk < K) ? A[(long)r * K + kk] : 0.f;
    }
#pragma unroll
    for (int l = 0; l < 4; ++l) {
      int idx = tid + l * 256;
      int j = idx >> 6, i = idx & 63;  // j: k in tile, i: col in tile
      int kk = k0 + j, c = col0 + i;
      Bs[j][i] = (kk < K && c < N) ? B[(long)kk * N + c] : 0.f;
    }
    __syncthreads();
#pragma unroll
    for (int kk = 0; kk < KT; ++kk) {
      float a[4], b[4];
#pragma unroll
      for (int r = 0; r < 4; ++r) a[r] = As[kk][ty * 4 + r];
#pragma unroll
      for (int c = 0; c < 4; ++c) b[c] = Bs[kk][tx * 4 + c];
#pragma unroll
      for (int r = 0; r < 4; ++r)
#pragma unroll
        for (int c = 0; c < 4; ++c) acc[r][c] += a[r] * b[c];
    }
    __syncthreads();
  }
#pragma unroll
  for (int r = 0; r < 4; ++r) {
    int row = row0 + ty * 4 + r;
    if (row >= M) continue;
#pragma unroll
    for (int c = 0; c < 4; ++c) {
      int col = col0 + tx * 4 + c;
      if (col >= N) continue;
      float v = acc[r][c];
      if (bias) v += bias[col];
      C[(long)row * N + col] = v;
    }
  }
}

// ---------------- BatchNorm: column stats then in-place apply + ELU ----------
__global__ __launch_bounds__(256) void bn_stats(
    const float* __restrict__ h, int M, int N,
    float* __restrict__ sum, float* __restrict__ sumsq) {
  int col = blockIdx.y * 256 + threadIdx.x;
  float s = 0.f, sq = 0.f;
  for (int r = blockIdx.x; r < M; r += gridDim.x) {
    float v = h[(long)r * N + col];
    s += v;
    sq += v * v;
  }
  atomicAdd(&sum[col], s);
  atomicAdd(&sumsq[col], sq);
}

__global__ __launch_bounds__(256) void bn_apply_elu(
    float* __restrict__ h, int M, int N,
    const float* __restrict__ sum, const float* __restrict__ sumsq,
    const float* __restrict__ g, const float* __restrict__ be) {
  long total = (long)M * N;
  float invM = 1.f / (float)M;
  for (long i = blockIdx.x * (long)blockDim.x + threadIdx.x; i < total;
       i += (long)gridDim.x * blockDim.x) {
    int col = (int)(i % N);
    float mean = sum[col] * invM;
    float var = sumsq[col] * invM - mean * mean;
    float v = (h[i] - mean) * rsqrtf(var + 1e-5f) * g[col] + be[col];
    h[i] = v > 0.f ? v : expm1f(v);
  }
}

// ---------------- GAT attention scores: a_src/a_dst [n, H] -------------------
__global__ __launch_bounds__(256) void att_scores(
    const float* __restrict__ hg, const float* __restrict__ att_s,
    const float* __restrict__ att_d, float* __restrict__ a_src,
    float* __restrict__ a_dst, int n) {
  int node = blockIdx.x;
  int head = threadIdx.x >> 6;
  int lane = threadIdx.x & 63;
  const float* row = hg + (long)node * 1024 + head * 256;
  const float* as = att_s + head * 256;
  const float* ad = att_d + head * 256;
  float ss = 0.f, sd = 0.f;
#pragma unroll
  for (int d = lane; d < 256; d += 64) {
    float v = row[d];
    ss += v * as[d];
    sd += v * ad[d];
  }
#pragma unroll
  for (int off = 32; off; off >>= 1) {
    ss += __shfl_down(ss, off);
    sd += __shfl_down(sd, off);
  }
  if (lane == 0) {
    a_src[node * 4 + head] = ss;
    a_dst[node * 4 + head] = sd;
  }
}

// ---------------- edge softmax: exp(e) and per-dst denominator --------------
__global__ __launch_bounds__(256) void edge_denom(
    const int* __restrict__ srcA, const int* __restrict__ dstA,
    const float* __restrict__ a_src, const float* __restrict__ a_dst,
    float* __restrict__ expe, float* __restrict__ denom, int n, int E0, int E) {
  int e = blockIdx.x * blockDim.x + threadIdx.x;
  if (e >= E) return;
  int s, d;
  if (e < E0) {
    s = srcA[e];
    d = dstA[e];
    if (s == d) d = (d + 1) % n;
  } else {
    s = d = e - E0;
  }
#pragma unroll
  for (int h = 0; h < 4; ++h) {
    float v = a_src[s * 4 + h] + a_dst[d * 4 + h];
    v = v > 0.f ? v : 0.2f * v;
    float ex = expf(v);
    expe[e * 4 + h] = ex;
    atomicAdd(&denom[d * 4 + h], ex);
  }
}

// ---------------- init output with broadcast bias ---------------------------
__global__ __launch_bounds__(256) void init_bias(
    float* __restrict__ out, const float* __restrict__ bias, int M, int N) {
  long total = (long)M * N;
  for (long i = blockIdx.x * (long)blockDim.x + threadIdx.x; i < total;
       i += (long)gridDim.x * blockDim.x)
    out[i] = bias[(int)(i % N)];
}

// ---------------- aggregation: out[dst] += hg[src] * alpha ------------------
__global__ __launch_bounds__(256) void aggregate(
    const float* __restrict__ hg, const int* __restrict__ srcA,
    const int* __restrict__ dstA, const float* __restrict__ expe,
    const float* __restrict__ denom, float* __restrict__ out, int n, int E0,
    int E) {
  int e = blockIdx.x;
  int s, d;
  if (e < E0) {
    s = srcA[e];
    d = dstA[e];
    if (s == d) d = (d + 1) % n;
  } else {
    s = d = e - E0;
  }
  int t = threadIdx.x;
#pragma unroll
  for (int h = 0; h < 4; ++h) {
    float alpha = expe[e * 4 + h] / (denom[d * 4 + h] + 1e-16f);
    int c = h * 256 + t;
    atomicAdd(&out[(long)d * 1024 + c], hg[(long)s * 1024 + c] * alpha);
  }
}

extern "C" void kernel_launch(void* const* d_in, const int* in_sizes, int n_in,
                              void* d_out, int out_size, void* d_ws,
                              size_t ws_size, hipStream_t stream) {
  const float* x = (const float*)d_in[0];
  const int* edges = (const int*)d_in[1];
  const float* W1 = (const float*)d_in[2];
  const float* b1 = (const float*)d_in[3];
  const float* W2 = (const float*)d_in[4];
  const float* b2 = (const float*)d_in[5];
  const float* W3 = (const float*)d_in[6];
  const float* b3 = (const float*)d_in[7];
  const float* g1 = (const float*)d_in[8];
  const float* be1 = (const float*)d_in[9];
  const float* g2 = (const float*)d_in[10];
  const float* be2 = (const float*)d_in[11];
  const float* g3 = (const float*)d_in[12];
  const float* be3 = (const float*)d_in[13];
  const float* g4 = (const float*)d_in[14];
  const float* be4 = (const float*)d_in[15];
  const float* Wg1 = (const float*)d_in[16];
  const float* as1 = (const float*)d_in[17];
  const float* ad1 = (const float*)d_in[18];
  const float* bg1 = (const float*)d_in[19];
  const float* Wg2 = (const float*)d_in[20];
  const float* as2 = (const float*)d_in[21];
  const float* ad2 = (const float*)d_in[22];
  const float* bg2 = (const float*)d_in[23];
  float* out = (float*)d_out;

  const int n = 10000, E0 = 160000, E = 170000;
  const int F = 2613, D = 256, HD = 1024;
  const int* srcA = edges;
  const int* dstA = edges + E0;

  float* ws = (float*)d_ws;
  float* hA = ws;                    // [n, 256]
  float* hB = hA + (long)n * D;      // [n, 256]
  float* hg = hB + (long)n * D;      // [n, 1024]
  float* agg = hg + (long)n * HD;    // [n, 1024]
  float* asrc = agg + (long)n * HD;  // [n, 4]
  float* adst = asrc + n * 4;        // [n, 4]
  float* expe = adst + n * 4;        // [E, 4]
  float* denom = expe + (long)E * 4; // [n, 4]
  float* ssum = denom + n * 4;       // [1024]
  float* ssq = ssum + 1024;          // [1024]

  dim3 blk(256);
  int rowBlocks = (n + BT - 1) / BT;  // 157

  // ---- MLP layer 1: hA = elu(bn(x@W1+b1)) ----
  gemm_f32<<<dim3(D / BT, rowBlocks), blk, 0, stream>>>(x, W1, b1, hA, n, D, F);
  hipMemsetAsync(ssum, 0, 2048 * sizeof(float), stream);
  bn_stats<<<dim3(64, D / 256), blk, 0, stream>>>(hA, n, D, ssum, ssq);
  bn_apply_elu<<<1024, blk, 0, stream>>>(hA, n, D, ssum, ssq, g1, be1);

  // ---- MLP layer 2: hB = elu(bn(hA@W2+b2)) ----
  gemm_f32<<<dim3(D / BT, rowBlocks), blk, 0, stream>>>(hA, W2, b2, hB, n, D, D);
  hipMemsetAsync(ssum, 0, 2048 * sizeof(float), stream);
  bn_stats<<<dim3(64, D / 256), blk, 0, stream>>>(hB, n, D, ssum, ssq);
  bn_apply_elu<<<1024, blk, 0, stream>>>(hB, n, D, ssum, ssq, g2, be2);

  // ---- MLP layer 3: hA = elu(bn(hB@W3+b3)) ----
  gemm_f32<<<dim3(D / BT, rowBlocks), blk, 0, stream>>>(hB, W3, b3, hA, n, D, D);
  hipMemsetAsync(ssum, 0, 2048 * sizeof(float), stream);
  bn_stats<<<dim3(64, D / 256), blk, 0, stream>>>(hA, n, D, ssum, ssq);
  bn_apply_elu<<<1024, blk, 0, stream>>>(hA, n, D, ssum, ssq, g3, be3);

  // ---- GAT layer 1 ----
  gemm_f32<<<dim3(HD / BT, rowBlocks), blk, 0, stream>>>(hA, Wg1, nullptr, hg,
                                                         n, HD, D);
  att_scores<<<n, blk, 0, stream>>>(hg, as1, ad1, asrc, adst, n);
  hipMemsetAsync(denom, 0, n * 4 * sizeof(float), stream);
  edge_denom<<<(E + 255) / 256, blk, 0, stream>>>(srcA, dstA, asrc, adst, expe,
                                                  denom, n, E0, E);
  init_bias<<<1024, blk, 0, stream>>>(agg, bg1, n, HD);
  aggregate<<<E, blk, 0, stream>>>(hg, srcA, dstA, expe, denom, agg, n, E0, E);

  // ---- BN4 + ELU on agg ----
  hipMemsetAsync(ssum, 0, 2048 * sizeof(float), stream);
  bn_stats<<<dim3(64, HD / 256), blk, 0, stream>>>(agg, n, HD, ssum, ssq);
  bn_apply_elu<<<2048, blk, 0, stream>>>(agg, n, HD, ssum, ssq, g4, be4);

  // ---- GAT layer 2 (writes d_out) ----
  gemm_f32<<<dim3(HD / BT, rowBlocks), blk, 0, stream>>>(agg, Wg2, nullptr, hg,
                                                         n, HD, HD);
  att_scores<<<n, blk, 0, stream>>>(hg, as2, ad2, asrc, adst, n);
  hipMemsetAsync(denom, 0, n * 4 * sizeof(float), stream);
  edge_denom<<<(E + 255) / 256, blk, 0, stream>>>(srcA, dstA, asrc, adst, expe,
                                                  denom, n, E0, E);
  init_bias<<<1024, blk, 0, stream>>>(out, bg2, n, HD);
  aggregate<<<E, blk, 0, stream>>>(hg, srcA, dstA, expe, denom, out, n, E0, E);
}

// Round 2
// 1760.341 us; speedup vs baseline: 1.4008x; 1.4008x over previous
//
#include <hip/hip_runtime.h>
#include <hip/hip_bf16.h>

typedef __attribute__((ext_vector_type(8))) short short8v;
typedef __attribute__((ext_vector_type(4))) float f32x4;

// ============ bf16-split MFMA GEMM: C[M,N] = A[M,Kp] @ Bt[N,Kp]^T ===========
// A given as hi/lo bf16 [M][Kp]; B given transposed hi/lo bf16 [N][Kp].
// C = Ah*Bh + Ah*Bl + Al*Bh  (al*bl dropped; rel err ~2^-17).
__global__ __launch_bounds__(256) void gemm_mfma_split(
    const __hip_bfloat16* __restrict__ Ah, const __hip_bfloat16* __restrict__ Al,
    const __hip_bfloat16* __restrict__ Bh, const __hip_bfloat16* __restrict__ Bl,
    const float* __restrict__ bias, float* __restrict__ C,
    int M, int N, int Kp) {
  __shared__ ushort Ash[128][40];
  __shared__ ushort Asl[128][40];
  __shared__ ushort Bsh[128][40];
  __shared__ ushort Bsl[128][40];
  const int tid = threadIdx.x;
  const int lane = tid & 63;
  const int w = tid >> 6;
  const int wr = w >> 1, wc = w & 1;
  const int brow = blockIdx.y * 128, bcol = blockIdx.x * 128;
  const int l15 = lane & 15;
  const int koff = (lane >> 4) * 8;

  // staging chunks: 512 x 16B per 128x32-bf16 tile; this thread does 2.
  const int r0 = tid >> 2, kq0 = (tid & 3) * 8;
  const int r1 = (tid + 256) >> 2, kq1 = ((tid + 256) & 3) * 8;

  f32x4 acc[4][4] = {};
  const short8v zz = {};
  const int nK = Kp >> 5;

  for (int ks = 0; ks < nK; ++ks) {
    const long k0 = (long)(ks << 5);
    const long ga0 = (long)(brow + r0) * Kp + k0, ga1 = (long)(brow + r1) * Kp + k0;
    const long gb0 = (long)(bcol + r0) * Kp + k0, gb1 = (long)(bcol + r1) * Kp + k0;
    const bool v0 = (brow + r0) < M, v1 = (brow + r1) < M;
    short8v ah0 = v0 ? *(const short8v*)(Ah + ga0 + kq0) : zz;
    short8v al0 = v0 ? *(const short8v*)(Al + ga0 + kq0) : zz;
    short8v ah1 = v1 ? *(const short8v*)(Ah + ga1 + kq1) : zz;
    short8v al1 = v1 ? *(const short8v*)(Al + ga1 + kq1) : zz;
    short8v bh0 = *(const short8v*)(Bh + gb0 + kq0);
    short8v bl0 = *(const short8v*)(Bl + gb0 + kq0);
    short8v bh1 = *(const short8v*)(Bh + gb1 + kq1);
    short8v bl1 = *(const short8v*)(Bl + gb1 + kq1);
    __syncthreads();  // previous iter's LDS reads done
    *(short8v*)&Ash[r0][kq0] = ah0;
    *(short8v*)&Asl[r0][kq0] = al0;
    *(short8v*)&Ash[r1][kq1] = ah1;
    *(short8v*)&Asl[r1][kq1] = al1;
    *(short8v*)&Bsh[r0][kq0] = bh0;
    *(short8v*)&Bsl[r0][kq0] = bl0;
    *(short8v*)&Bsh[r1][kq1] = bh1;
    *(short8v*)&Bsl[r1][kq1] = bl1;
    __syncthreads();

    short8v bfh[4], bfl[4];
#pragma unroll
    for (int nn = 0; nn < 4; ++nn) {
      bfh[nn] = *(const short8v*)&Bsh[wc * 64 + nn * 16 + l15][koff];
      bfl[nn] = *(const short8v*)&Bsl[wc * 64 + nn * 16 + l15][koff];
    }
#pragma unroll
    for (int m = 0; m < 4; ++m) {
      short8v afh = *(const short8v*)&Ash[wr * 64 + m * 16 + l15][koff];
      short8v afl = *(const short8v*)&Asl[wr * 64 + m * 16 + l15][koff];
#pragma unroll
      for (int nn = 0; nn < 4; ++nn) {
        acc[m][nn] = __builtin_amdgcn_mfma_f32_16x16x32_bf16(afh, bfh[nn], acc[m][nn], 0, 0, 0);
        acc[m][nn] = __builtin_amdgcn_mfma_f32_16x16x32_bf16(afh, bfl[nn], acc[m][nn], 0, 0, 0);
        acc[m][nn] = __builtin_amdgcn_mfma_f32_16x16x32_bf16(afl, bfh[nn], acc[m][nn], 0, 0, 0);
      }
    }
  }

#pragma unroll
  for (int m = 0; m < 4; ++m) {
#pragma unroll
    for (int nn = 0; nn < 4; ++nn) {
      int col = bcol + wc * 64 + nn * 16 + l15;
      float bv = bias ? bias[col] : 0.f;
#pragma unroll
      for (int r = 0; r < 4; ++r) {
        int row = brow + wr * 64 + m * 16 + (lane >> 4) * 4 + r;
        if (row < M) C[(long)row * N + col] = acc[m][nn][r] + bv;
      }
    }
  }
}

// ============ split fp32 -> bf16 hi/lo, row-major with K padding =============
__global__ __launch_bounds__(256) void split_pad(
    const float* __restrict__ A, __hip_bfloat16* __restrict__ Oh,
    __hip_bfloat16* __restrict__ Ol, int K, int Kp) {
  int r = blockIdx.y;
  int k = blockIdx.x * 256 + threadIdx.x;
  if (k >= Kp) return;
  float v = (k < K) ? A[(long)r * K + k] : 0.f;
  __hip_bfloat16 hi = __float2bfloat16(v);
  __hip_bfloat16 lo = __float2bfloat16(v - __bfloat162float(hi));
  Oh[(long)r * Kp + k] = hi;
  Ol[(long)r * Kp + k] = lo;
}

// ============ split + transpose weight: W[K][N] -> Wt hi/lo [N][Kp] ==========
__global__ __launch_bounds__(256) void split_transpose(
    const float* __restrict__ W, __hip_bfloat16* __restrict__ Oh,
    __hip_bfloat16* __restrict__ Ol, int K, int N, int Kp) {
  int n = blockIdx.y;
  int k = blockIdx.x * 256 + threadIdx.x;
  if (k >= Kp) return;
  float v = (k < K) ? W[(long)k * N + n] : 0.f;
  __hip_bfloat16 hi = __float2bfloat16(v);
  __hip_bfloat16 lo = __float2bfloat16(v - __bfloat162float(hi));
  Oh[(long)n * Kp + k] = hi;
  Ol[(long)n * Kp + k] = lo;
}

// ============ BatchNorm stats ================================================
__global__ __launch_bounds__(256) void bn_stats(
    const float* __restrict__ h, int M, int N,
    float* __restrict__ sum, float* __restrict__ sumsq) {
  int col = blockIdx.y * 256 + threadIdx.x;
  float s = 0.f, sq = 0.f;
  for (int r = blockIdx.x; r < M; r += gridDim.x) {
    float v = h[(long)r * N + col];
    s += v;
    sq += v * v;
  }
  atomicAdd(&sum[col], s);
  atomicAdd(&sumsq[col], sq);
}

// ============ BN apply + ELU, also emit bf16 hi/lo split =====================
__global__ __launch_bounds__(256) void bn_apply_elu_split(
    float* __restrict__ h, int M, int N,
    const float* __restrict__ sum, const float* __restrict__ sumsq,
    const float* __restrict__ g, const float* __restrict__ be,
    __hip_bfloat16* __restrict__ oh, __hip_bfloat16* __restrict__ ol) {
  long total = (long)M * N;
  float invM = 1.f / (float)M;
  for (long i = blockIdx.x * (long)blockDim.x + threadIdx.x; i < total;
       i += (long)gridDim.x * blockDim.x) {
    int col = (int)(i % N);
    float mean = sum[col] * invM;
    float var = sumsq[col] * invM - mean * mean;
    float v = (h[i] - mean) * rsqrtf(var + 1e-5f) * g[col] + be[col];
    v = v > 0.f ? v : expm1f(v);
    h[i] = v;
    __hip_bfloat16 hi = __float2bfloat16(v);
    oh[i] = hi;
    ol[i] = __float2bfloat16(v - __bfloat162float(hi));
  }
}

// ============ GAT attention scores ===========================================
__global__ __launch_bounds__(256) void att_scores(
    const float* __restrict__ hg, const float* __restrict__ att_s,
    const float* __restrict__ att_d, float* __restrict__ a_src,
    float* __restrict__ a_dst, int n) {
  int node = blockIdx.x;
  int head = threadIdx.x >> 6;
  int lane = threadIdx.x & 63;
  const float* row = hg + (long)node * 1024 + head * 256;
  const float* as = att_s + head * 256;
  const float* ad = att_d + head * 256;
  float ss = 0.f, sd = 0.f;
#pragma unroll
  for (int d = lane; d < 256; d += 64) {
    float v = row[d];
    ss += v * as[d];
    sd += v * ad[d];
  }
#pragma unroll
  for (int off = 32; off; off >>= 1) {
    ss += __shfl_down(ss, off);
    sd += __shfl_down(sd, off);
  }
  if (lane == 0) {
    a_src[node * 4 + head] = ss;
    a_dst[node * 4 + head] = sd;
  }
}

// ============ edge softmax: exp(e) and per-dst denominator ===================
__global__ __launch_bounds__(256) void edge_denom(
    const int* __restrict__ srcA, const int* __restrict__ dstA,
    const float* __restrict__ a_src, const float* __restrict__ a_dst,
    float* __restrict__ expe, float* __restrict__ denom, int n, int E0, int E) {
  int e = blockIdx.x * blockDim.x + threadIdx.x;
  if (e >= E) return;
  int s, d;
  if (e < E0) {
    s = srcA[e];
    d = dstA[e];
    if (s == d) d = (d + 1) % n;
  } else {
    s = d = e - E0;
  }
#pragma unroll
  for (int h = 0; h < 4; ++h) {
    float v = a_src[s * 4 + h] + a_dst[d * 4 + h];
    v = v > 0.f ? v : 0.2f * v;
    float ex = expf(v);
    expe[e * 4 + h] = ex;
    atomicAdd(&denom[d * 4 + h], ex);
  }
}

// ============ init output with broadcast bias ================================
__global__ __launch_bounds__(256) void init_bias(
    float* __restrict__ out, const float* __restrict__ bias, int M, int N) {
  long total = (long)M * N;
  for (long i = blockIdx.x * (long)blockDim.x + threadIdx.x; i < total;
       i += (long)gridDim.x * blockDim.x)
    out[i] = bias[(int)(i % N)];
}

// ============ aggregation: out[dst] += hg[src] * alpha =======================
__global__ __launch_bounds__(256) void aggregate(
    const float* __restrict__ hg, const int* __restrict__ srcA,
    const int* __restrict__ dstA, const float* __restrict__ expe,
    const float* __restrict__ denom, float* __restrict__ out, int n, int E0,
    int E) {
  int e = blockIdx.x;
  int s, d;
  if (e < E0) {
    s = srcA[e];
    d = dstA[e];
    if (s == d) d = (d + 1) % n;
  } else {
    s = d = e - E0;
  }
  int t = threadIdx.x;
#pragma unroll
  for (int h = 0; h < 4; ++h) {
    float alpha = expe[e * 4 + h] / (denom[d * 4 + h] + 1e-16f);
    int c = h * 256 + t;
    atomicAdd(&out[(long)d * 1024 + c], hg[(long)s * 1024 + c] * alpha);
  }
}

extern "C" void kernel_launch(void* const* d_in, const int* in_sizes, int n_in,
                              void* d_out, int out_size, void* d_ws,
                              size_t ws_size, hipStream_t stream) {
  const float* x = (const float*)d_in[0];
  const int* edges = (const int*)d_in[1];
  const float* W1 = (const float*)d_in[2];
  const float* b1 = (const float*)d_in[3];
  const float* W2 = (const float*)d_in[4];
  const float* b2 = (const float*)d_in[5];
  const float* W3 = (const float*)d_in[6];
  const float* b3 = (const float*)d_in[7];
  const float* g1 = (const float*)d_in[8];
  const float* be1 = (const float*)d_in[9];
  const float* g2 = (const float*)d_in[10];
  const float* be2 = (const float*)d_in[11];
  const float* g3 = (const float*)d_in[12];
  const float* be3 = (const float*)d_in[13];
  const float* g4 = (const float*)d_in[14];
  const float* be4 = (const float*)d_in[15];
  const float* Wg1 = (const float*)d_in[16];
  const float* as1 = (const float*)d_in[17];
  const float* ad1 = (const float*)d_in[18];
  const float* bg1 = (const float*)d_in[19];
  const float* Wg2 = (const float*)d_in[20];
  const float* as2 = (const float*)d_in[21];
  const float* ad2 = (const float*)d_in[22];
  const float* bg2 = (const float*)d_in[23];
  float* out = (float*)d_out;

  const int n = 10000, E0 = 160000, E = 170000;
  const int F = 2613, Fp = 2624, D = 256, HD = 1024;
  const int* srcA = edges;
  const int* dstA = edges + E0;

  // ---- workspace layout (bump allocator, 256B aligned) ----
  uint8_t* p = (uint8_t*)d_ws;
  auto alloc = [&](size_t bytes) -> void* {
    void* r = (void*)p;
    p += (bytes + 255) & ~(size_t)255;
    return r;
  };
  float* hA = (float*)alloc((size_t)n * D * 4);
  float* hB = (float*)alloc((size_t)n * D * 4);
  float* hg = (float*)alloc((size_t)n * HD * 4);
  float* agg = (float*)alloc((size_t)n * HD * 4);
  __hip_bfloat16* xh = (__hip_bfloat16*)alloc((size_t)n * Fp * 2);
  __hip_bfloat16* xl = (__hip_bfloat16*)alloc((size_t)n * Fp * 2);
  // hsp aliases x-split region (x-split is dead after gemm1, bn1 runs later)
  __hip_bfloat16* hsph = xh;
  __hip_bfloat16* hspl = xl;
  __hip_bfloat16* W1h = (__hip_bfloat16*)alloc((size_t)D * Fp * 2);
  __hip_bfloat16* W1l = (__hip_bfloat16*)alloc((size_t)D * Fp * 2);
  __hip_bfloat16* W2h = (__hip_bfloat16*)alloc((size_t)D * D * 2);
  __hip_bfloat16* W2l = (__hip_bfloat16*)alloc((size_t)D * D * 2);
  __hip_bfloat16* W3h = (__hip_bfloat16*)alloc((size_t)D * D * 2);
  __hip_bfloat16* W3l = (__hip_bfloat16*)alloc((size_t)D * D * 2);
  __hip_bfloat16* Wg1h = (__hip_bfloat16*)alloc((size_t)HD * D * 2);
  __hip_bfloat16* Wg1l = (__hip_bfloat16*)alloc((size_t)HD * D * 2);
  __hip_bfloat16* Wg2h = (__hip_bfloat16*)alloc((size_t)HD * HD * 2);
  __hip_bfloat16* Wg2l = (__hip_bfloat16*)alloc((size_t)HD * HD * 2);
  float* asrc = (float*)alloc((size_t)n * 4 * 4);
  float* adst = (float*)alloc((size_t)n * 4 * 4);
  float* denom = (float*)alloc((size_t)n * 4 * 4);
  float* expe = (float*)alloc((size_t)E * 4 * 4);
  float* ssum = (float*)alloc(1024 * 4);
  float* ssq = (float*)alloc(1024 * 4);

  dim3 blk(256);
  int rb = (n + 127) / 128;  // 79 row blocks

  // ---- one-time splits ----
  split_pad<<<dim3((Fp + 255) / 256, n), blk, 0, stream>>>(x, xh, xl, F, Fp);
  split_transpose<<<dim3((Fp + 255) / 256, D), blk, 0, stream>>>(W1, W1h, W1l, F, D, Fp);
  split_transpose<<<dim3(1, D), blk, 0, stream>>>(W2, W2h, W2l, D, D, D);
  split_transpose<<<dim3(1, D), blk, 0, stream>>>(W3, W3h, W3l, D, D, D);
  split_transpose<<<dim3(1, HD), blk, 0, stream>>>(Wg1, Wg1h, Wg1l, D, HD, D);
  split_transpose<<<dim3(4, HD), blk, 0, stream>>>(Wg2, Wg2h, Wg2l, HD, HD, HD);

  // ---- MLP layer 1 ----
  gemm_mfma_split<<<dim3(D / 128, rb), blk, 0, stream>>>(xh, xl, W1h, W1l, b1, hA, n, D, Fp);
  hipMemsetAsync(ssum, 0, 2048 * sizeof(float), stream);
  bn_stats<<<dim3(64, D / 256), blk, 0, stream>>>(hA, n, D, ssum, ssq);
  bn_apply_elu_split<<<1024, blk, 0, stream>>>(hA, n, D, ssum, ssq, g1, be1, hsph, hspl);

  // ---- MLP layer 2 ----
  gemm_mfma_split<<<dim3(D / 128, rb), blk, 0, stream>>>(hsph, hspl, W2h, W2l, b2, hB, n, D, D);
  hipMemsetAsync(ssum, 0, 2048 * sizeof(float), stream);
  bn_stats<<<dim3(64, D / 256), blk, 0, stream>>>(hB, n, D, ssum, ssq);
  bn_apply_elu_split<<<1024, blk, 0, stream>>>(hB, n, D, ssum, ssq, g2, be2, hsph, hspl);

  // ---- MLP layer 3 ----
  gemm_mfma_split<<<dim3(D / 128, rb), blk, 0, stream>>>(hsph, hspl, W3h, W3l, b3, hA, n, D, D);
  hipMemsetAsync(ssum, 0, 2048 * sizeof(float), stream);
  bn_stats<<<dim3(64, D / 256), blk, 0, stream>>>(hA, n, D, ssum, ssq);
  bn_apply_elu_split<<<1024, blk, 0, stream>>>(hA, n, D, ssum, ssq, g3, be3, hsph, hspl);

  // ---- GAT layer 1 ----
  gemm_mfma_split<<<dim3(HD / 128, rb), blk, 0, stream>>>(hsph, hspl, Wg1h, Wg1l, nullptr, hg, n, HD, D);
  att_scores<<<n, blk, 0, stream>>>(hg, as1, ad1, asrc, adst, n);
  hipMemsetAsync(denom, 0, n * 4 * sizeof(float), stream);
  edge_denom<<<(E + 255) / 256, blk, 0, stream>>>(srcA, dstA, asrc, adst, expe, denom, n, E0, E);
  init_bias<<<1024, blk, 0, stream>>>(agg, bg1, n, HD);
  aggregate<<<E, blk, 0, stream>>>(hg, srcA, dstA, expe, denom, agg, n, E0, E);

  // ---- BN4 + ELU (emits split for gat2's GEMM) ----
  hipMemsetAsync(ssum, 0, 2048 * sizeof(float), stream);
  bn_stats<<<dim3(64, HD / 256), blk, 0, stream>>>(agg, n, HD, ssum, ssq);
  bn_apply_elu_split<<<2048, blk, 0, stream>>>(agg, n, HD, ssum, ssq, g4, be4, hsph, hspl);

  // ---- GAT layer 2 (writes d_out) ----
  gemm_mfma_split<<<dim3(HD / 128, rb), blk, 0, stream>>>(hsph, hspl, Wg2h, Wg2l, nullptr, hg, n, HD, HD);
  att_scores<<<n, blk, 0, stream>>>(hg, as2, ad2, asrc, adst, n);
  hipMemsetAsync(denom, 0, n * 4 * sizeof(float), stream);
  edge_denom<<<(E + 255) / 256, blk, 0, stream>>>(srcA, dstA, asrc, adst, expe, denom, n, E0, E);
  init_bias<<<1024, blk, 0, stream>>>(out, bg2, n, HD);
  aggregate<<<E, blk, 0, stream>>>(hg, srcA, dstA, expe, denom, out, n, E0, E);
}

// Round 3
// 918.824 us; speedup vs baseline: 2.6838x; 1.9159x over previous
//
#include <hip/hip_runtime.h>
#include <hip/hip_bf16.h>

typedef __attribute__((ext_vector_type(8))) short short8v;
typedef __attribute__((ext_vector_type(4))) float f32x4;

// ============ bf16-split MFMA GEMM: C[M,N] = A[M,Kp] @ Bt[N,Kp]^T ===========
// A given as hi/lo bf16 [M][Kp]; B given transposed hi/lo bf16 [N][Kp].
// C = Ah*Bh + Ah*Bl + Al*Bh  (al*bl dropped; rel err ~2^-17).
__global__ __launch_bounds__(256) void gemm_mfma_split(
    const __hip_bfloat16* __restrict__ Ah, const __hip_bfloat16* __restrict__ Al,
    const __hip_bfloat16* __restrict__ Bh, const __hip_bfloat16* __restrict__ Bl,
    const float* __restrict__ bias, float* __restrict__ C,
    int M, int N, int Kp) {
  __shared__ ushort Ash[128][40];
  __shared__ ushort Asl[128][40];
  __shared__ ushort Bsh[128][40];
  __shared__ ushort Bsl[128][40];
  const int tid = threadIdx.x;
  const int lane = tid & 63;
  const int w = tid >> 6;
  const int wr = w >> 1, wc = w & 1;
  const int brow = blockIdx.y * 128, bcol = blockIdx.x * 128;
  const int l15 = lane & 15;
  const int koff = (lane >> 4) * 8;

  const int r0 = tid >> 2, kq0 = (tid & 3) * 8;
  const int r1 = (tid + 256) >> 2, kq1 = ((tid + 256) & 3) * 8;

  f32x4 acc[4][4] = {};
  const short8v zz = {};
  const int nK = Kp >> 5;

  for (int ks = 0; ks < nK; ++ks) {
    const long k0 = (long)(ks << 5);
    const long ga0 = (long)(brow + r0) * Kp + k0, ga1 = (long)(brow + r1) * Kp + k0;
    const long gb0 = (long)(bcol + r0) * Kp + k0, gb1 = (long)(bcol + r1) * Kp + k0;
    const bool v0 = (brow + r0) < M, v1 = (brow + r1) < M;
    short8v ah0 = v0 ? *(const short8v*)(Ah + ga0 + kq0) : zz;
    short8v al0 = v0 ? *(const short8v*)(Al + ga0 + kq0) : zz;
    short8v ah1 = v1 ? *(const short8v*)(Ah + ga1 + kq1) : zz;
    short8v al1 = v1 ? *(const short8v*)(Al + ga1 + kq1) : zz;
    short8v bh0 = *(const short8v*)(Bh + gb0 + kq0);
    short8v bl0 = *(const short8v*)(Bl + gb0 + kq0);
    short8v bh1 = *(const short8v*)(Bh + gb1 + kq1);
    short8v bl1 = *(const short8v*)(Bl + gb1 + kq1);
    __syncthreads();
    *(short8v*)&Ash[r0][kq0] = ah0;
    *(short8v*)&Asl[r0][kq0] = al0;
    *(short8v*)&Ash[r1][kq1] = ah1;
    *(short8v*)&Asl[r1][kq1] = al1;
    *(short8v*)&Bsh[r0][kq0] = bh0;
    *(short8v*)&Bsl[r0][kq0] = bl0;
    *(short8v*)&Bsh[r1][kq1] = bh1;
    *(short8v*)&Bsl[r1][kq1] = bl1;
    __syncthreads();

    short8v bfh[4], bfl[4];
#pragma unroll
    for (int nn = 0; nn < 4; ++nn) {
      bfh[nn] = *(const short8v*)&Bsh[wc * 64 + nn * 16 + l15][koff];
      bfl[nn] = *(const short8v*)&Bsl[wc * 64 + nn * 16 + l15][koff];
    }
#pragma unroll
    for (int m = 0; m < 4; ++m) {
      short8v afh = *(const short8v*)&Ash[wr * 64 + m * 16 + l15][koff];
      short8v afl = *(const short8v*)&Asl[wr * 64 + m * 16 + l15][koff];
#pragma unroll
      for (int nn = 0; nn < 4; ++nn) {
        acc[m][nn] = __builtin_amdgcn_mfma_f32_16x16x32_bf16(afh, bfh[nn], acc[m][nn], 0, 0, 0);
        acc[m][nn] = __builtin_amdgcn_mfma_f32_16x16x32_bf16(afh, bfl[nn], acc[m][nn], 0, 0, 0);
        acc[m][nn] = __builtin_amdgcn_mfma_f32_16x16x32_bf16(afl, bfh[nn], acc[m][nn], 0, 0, 0);
      }
    }
  }

#pragma unroll
  for (int m = 0; m < 4; ++m) {
#pragma unroll
    for (int nn = 0; nn < 4; ++nn) {
      int col = bcol + wc * 64 + nn * 16 + l15;
      float bv = bias ? bias[col] : 0.f;
#pragma unroll
      for (int r = 0; r < 4; ++r) {
        int row = brow + wr * 64 + m * 16 + (lane >> 4) * 4 + r;
        if (row < M) C[(long)row * N + col] = acc[m][nn][r] + bv;
      }
    }
  }
}

// ============ split fp32 -> bf16 hi/lo, row-major with K padding =============
__global__ __launch_bounds__(256) void split_pad(
    const float* __restrict__ A, __hip_bfloat16* __restrict__ Oh,
    __hip_bfloat16* __restrict__ Ol, int K, int Kp) {
  int r = blockIdx.y;
  int k = blockIdx.x * 256 + threadIdx.x;
  if (k >= Kp) return;
  float v = (k < K) ? A[(long)r * K + k] : 0.f;
  __hip_bfloat16 hi = __float2bfloat16(v);
  __hip_bfloat16 lo = __float2bfloat16(v - __bfloat162float(hi));
  Oh[(long)r * Kp + k] = hi;
  Ol[(long)r * Kp + k] = lo;
}

// ============ split + transpose weight: W[K][N] -> Wt hi/lo [N][Kp] ==========
__global__ __launch_bounds__(256) void split_transpose(
    const float* __restrict__ W, __hip_bfloat16* __restrict__ Oh,
    __hip_bfloat16* __restrict__ Ol, int K, int N, int Kp) {
  int n = blockIdx.y;
  int k = blockIdx.x * 256 + threadIdx.x;
  if (k >= Kp) return;
  float v = (k < K) ? W[(long)k * N + n] : 0.f;
  __hip_bfloat16 hi = __float2bfloat16(v);
  __hip_bfloat16 lo = __float2bfloat16(v - __bfloat162float(hi));
  Oh[(long)n * Kp + k] = hi;
  Ol[(long)n * Kp + k] = lo;
}

// ============ BatchNorm stats ================================================
__global__ __launch_bounds__(256) void bn_stats(
    const float* __restrict__ h, int M, int N,
    float* __restrict__ sum, float* __restrict__ sumsq) {
  int col = blockIdx.y * 256 + threadIdx.x;
  float s = 0.f, sq = 0.f;
  for (int r = blockIdx.x; r < M; r += gridDim.x) {
    float v = h[(long)r * N + col];
    s += v;
    sq += v * v;
  }
  atomicAdd(&sum[col], s);
  atomicAdd(&sumsq[col], sq);
}

// ============ BN apply + ELU, also emit bf16 hi/lo split =====================
__global__ __launch_bounds__(256) void bn_apply_elu_split(
    float* __restrict__ h, int M, int N,
    const float* __restrict__ sum, const float* __restrict__ sumsq,
    const float* __restrict__ g, const float* __restrict__ be,
    __hip_bfloat16* __restrict__ oh, __hip_bfloat16* __restrict__ ol) {
  long total = (long)M * N;
  float invM = 1.f / (float)M;
  for (long i = blockIdx.x * (long)blockDim.x + threadIdx.x; i < total;
       i += (long)gridDim.x * blockDim.x) {
    int col = (int)(i % N);
    float mean = sum[col] * invM;
    float var = sumsq[col] * invM - mean * mean;
    float v = (h[i] - mean) * rsqrtf(var + 1e-5f) * g[col] + be[col];
    v = v > 0.f ? v : expm1f(v);
    h[i] = v;
    __hip_bfloat16 hi = __float2bfloat16(v);
    oh[i] = hi;
    ol[i] = __float2bfloat16(v - __bfloat162float(hi));
  }
}

// ============ GAT attention scores ===========================================
__global__ __launch_bounds__(256) void att_scores(
    const float* __restrict__ hg, const float* __restrict__ att_s,
    const float* __restrict__ att_d, float* __restrict__ a_src,
    float* __restrict__ a_dst, int n) {
  int node = blockIdx.x;
  int head = threadIdx.x >> 6;
  int lane = threadIdx.x & 63;
  const float* row = hg + (long)node * 1024 + head * 256;
  const float* as = att_s + head * 256;
  const float* ad = att_d + head * 256;
  float ss = 0.f, sd = 0.f;
#pragma unroll
  for (int d = lane; d < 256; d += 64) {
    float v = row[d];
    ss += v * as[d];
    sd += v * ad[d];
  }
#pragma unroll
  for (int off = 32; off; off >>= 1) {
    ss += __shfl_down(ss, off);
    sd += __shfl_down(sd, off);
  }
  if (lane == 0) {
    a_src[node * 4 + head] = ss;
    a_dst[node * 4 + head] = sd;
  }
}

// ============ edge softmax: exp(e) and per-dst denominator ===================
__global__ __launch_bounds__(256) void edge_denom(
    const int* __restrict__ srcA, const int* __restrict__ dstA,
    const float* __restrict__ a_src, const float* __restrict__ a_dst,
    float* __restrict__ expe, float* __restrict__ denom, int n, int E0, int E) {
  int e = blockIdx.x * blockDim.x + threadIdx.x;
  if (e >= E) return;
  int s, d;
  if (e < E0) {
    s = srcA[e];
    d = dstA[e];
    if (s == d) d = (d + 1) % n;
  } else {
    s = d = e - E0;
  }
#pragma unroll
  for (int h = 0; h < 4; ++h) {
    float v = a_src[s * 4 + h] + a_dst[d * 4 + h];
    v = v > 0.f ? v : 0.2f * v;
    float ex = expf(v);
    expe[e * 4 + h] = ex;
    atomicAdd(&denom[d * 4 + h], ex);
  }
}

// ============ CSR build: degree histogram ====================================
__global__ __launch_bounds__(256) void deg_count(
    const int* __restrict__ srcA, const int* __restrict__ dstA,
    int* __restrict__ deg, int n, int E0, int E) {
  int e = blockIdx.x * blockDim.x + threadIdx.x;
  if (e >= E) return;
  int d;
  if (e < E0) {
    int s = srcA[e];
    d = dstA[e];
    if (s == d) d = (d + 1) % n;
  } else {
    d = e - E0;
  }
  atomicAdd(&deg[d], 1);
}

// ============ CSR build: exclusive scan (single block) =======================
__global__ __launch_bounds__(256) void scan_rows(
    const int* __restrict__ deg, int* __restrict__ row_start, int n) {
  __shared__ int sums[256];
  int t = threadIdx.x;
  int chunk = (n + 255) / 256;
  int start = t * chunk, end = min(start + chunk, n);
  int s = 0;
  for (int i = start; i < end; ++i) s += deg[i];
  sums[t] = s;
  __syncthreads();
  for (int off = 1; off < 256; off <<= 1) {
    int v = (t >= off) ? sums[t - off] : 0;
    __syncthreads();
    sums[t] += v;
    __syncthreads();
  }
  int run = (t == 0) ? 0 : sums[t - 1];
  for (int i = start; i < end; ++i) {
    row_start[i] = run;
    run += deg[i];
  }
  if (t == 255) row_start[n] = run;
}

// ============ CSR build: scatter edges by destination ========================
__global__ __launch_bounds__(256) void scatter_edges(
    const int* __restrict__ srcA, const int* __restrict__ dstA,
    int* __restrict__ cursor, int* __restrict__ csr_src,
    int* __restrict__ csr_eid, int n, int E0, int E) {
  int e = blockIdx.x * blockDim.x + threadIdx.x;
  if (e >= E) return;
  int s, d;
  if (e < E0) {
    s = srcA[e];
    d = dstA[e];
    if (s == d) d = (d + 1) % n;
  } else {
    s = d = e - E0;
  }
  int pos = atomicAdd(&cursor[d], 1);
  csr_src[pos] = s;
  csr_eid[pos] = e;
}

// ============ gather aggregation: one block per dst node =====================
__global__ __launch_bounds__(256) void aggregate_csr(
    const float* __restrict__ hg, const int* __restrict__ row_start,
    const int* __restrict__ csr_src, const int* __restrict__ csr_eid,
    const float* __restrict__ expe, const float* __restrict__ denom,
    const float* __restrict__ bias, float* __restrict__ out) {
  int d = blockIdx.x;
  int t = threadIdx.x;
  int p0 = row_start[d], p1 = row_start[d + 1];
  float rden[4], acc[4];
#pragma unroll
  for (int h = 0; h < 4; ++h) {
    rden[h] = 1.f / (denom[d * 4 + h] + 1e-16f);
    acc[h] = bias[h * 256 + t];
  }
  for (int p = p0; p < p1; ++p) {
    int s = csr_src[p];
    int e = csr_eid[p];
#pragma unroll
    for (int h = 0; h < 4; ++h) {
      float a = expe[e * 4 + h] * rden[h];
      acc[h] += hg[(long)s * 1024 + h * 256 + t] * a;
    }
  }
#pragma unroll
  for (int h = 0; h < 4; ++h) out[(long)d * 1024 + h * 256 + t] = acc[h];
}

extern "C" void kernel_launch(void* const* d_in, const int* in_sizes, int n_in,
                              void* d_out, int out_size, void* d_ws,
                              size_t ws_size, hipStream_t stream) {
  const float* x = (const float*)d_in[0];
  const int* edges = (const int*)d_in[1];
  const float* W1 = (const float*)d_in[2];
  const float* b1 = (const float*)d_in[3];
  const float* W2 = (const float*)d_in[4];
  const float* b2 = (const float*)d_in[5];
  const float* W3 = (const float*)d_in[6];
  const float* b3 = (const float*)d_in[7];
  const float* g1 = (const float*)d_in[8];
  const float* be1 = (const float*)d_in[9];
  const float* g2 = (const float*)d_in[10];
  const float* be2 = (const float*)d_in[11];
  const float* g3 = (const float*)d_in[12];
  const float* be3 = (const float*)d_in[13];
  const float* g4 = (const float*)d_in[14];
  const float* be4 = (const float*)d_in[15];
  const float* Wg1 = (const float*)d_in[16];
  const float* as1 = (const float*)d_in[17];
  const float* ad1 = (const float*)d_in[18];
  const float* bg1 = (const float*)d_in[19];
  const float* Wg2 = (const float*)d_in[20];
  const float* as2 = (const float*)d_in[21];
  const float* ad2 = (const float*)d_in[22];
  const float* bg2 = (const float*)d_in[23];
  float* out = (float*)d_out;

  const int n = 10000, E0 = 160000, E = 170000;
  const int F = 2613, Fp = 2624, D = 256, HD = 1024;
  const int* srcA = edges;
  const int* dstA = edges + E0;

  // ---- workspace layout (bump allocator, 256B aligned) ----
  uint8_t* p = (uint8_t*)d_ws;
  auto alloc = [&](size_t bytes) -> void* {
    void* r = (void*)p;
    p += (bytes + 255) & ~(size_t)255;
    return r;
  };
  float* hA = (float*)alloc((size_t)n * D * 4);
  float* hB = (float*)alloc((size_t)n * D * 4);
  float* hg = (float*)alloc((size_t)n * HD * 4);
  float* agg = (float*)alloc((size_t)n * HD * 4);
  __hip_bfloat16* xh = (__hip_bfloat16*)alloc((size_t)n * Fp * 2);
  __hip_bfloat16* xl = (__hip_bfloat16*)alloc((size_t)n * Fp * 2);
  __hip_bfloat16* hsph = xh;  // alias: x-split dead after gemm1
  __hip_bfloat16* hspl = xl;
  __hip_bfloat16* W1h = (__hip_bfloat16*)alloc((size_t)D * Fp * 2);
  __hip_bfloat16* W1l = (__hip_bfloat16*)alloc((size_t)D * Fp * 2);
  __hip_bfloat16* W2h = (__hip_bfloat16*)alloc((size_t)D * D * 2);
  __hip_bfloat16* W2l = (__hip_bfloat16*)alloc((size_t)D * D * 2);
  __hip_bfloat16* W3h = (__hip_bfloat16*)alloc((size_t)D * D * 2);
  __hip_bfloat16* W3l = (__hip_bfloat16*)alloc((size_t)D * D * 2);
  __hip_bfloat16* Wg1h = (__hip_bfloat16*)alloc((size_t)HD * D * 2);
  __hip_bfloat16* Wg1l = (__hip_bfloat16*)alloc((size_t)HD * D * 2);
  __hip_bfloat16* Wg2h = (__hip_bfloat16*)alloc((size_t)HD * HD * 2);
  __hip_bfloat16* Wg2l = (__hip_bfloat16*)alloc((size_t)HD * HD * 2);
  float* asrc = (float*)alloc((size_t)n * 4 * 4);
  float* adst = (float*)alloc((size_t)n * 4 * 4);
  float* denom = (float*)alloc((size_t)n * 4 * 4);
  float* expe = (float*)alloc((size_t)E * 4 * 4);
  float* ssum = (float*)alloc(1024 * 4);
  float* ssq = (float*)alloc(1024 * 4);
  int* deg = (int*)alloc((size_t)n * 4);
  int* row_start = (int*)alloc((size_t)(n + 1) * 4);
  int* cursor = (int*)alloc((size_t)n * 4);
  int* csr_src = (int*)alloc((size_t)E * 4);
  int* csr_eid = (int*)alloc((size_t)E * 4);

  dim3 blk(256);
  int rb = (n + 127) / 128;  // 79 row blocks
  int eb = (E + 255) / 256;

  // ---- CSR build (depends only on edges; reused by both GAT layers) ----
  hipMemsetAsync(deg, 0, n * sizeof(int), stream);
  deg_count<<<eb, blk, 0, stream>>>(srcA, dstA, deg, n, E0, E);
  scan_rows<<<1, blk, 0, stream>>>(deg, row_start, n);
  hipMemcpyAsync(cursor, row_start, n * sizeof(int), hipMemcpyDeviceToDevice, stream);
  scatter_edges<<<eb, blk, 0, stream>>>(srcA, dstA, cursor, csr_src, csr_eid, n, E0, E);

  // ---- one-time splits ----
  split_pad<<<dim3((Fp + 255) / 256, n), blk, 0, stream>>>(x, xh, xl, F, Fp);
  split_transpose<<<dim3((Fp + 255) / 256, D), blk, 0, stream>>>(W1, W1h, W1l, F, D, Fp);
  split_transpose<<<dim3(1, D), blk, 0, stream>>>(W2, W2h, W2l, D, D, D);
  split_transpose<<<dim3(1, D), blk, 0, stream>>>(W3, W3h, W3l, D, D, D);
  split_transpose<<<dim3(1, HD), blk, 0, stream>>>(Wg1, Wg1h, Wg1l, D, HD, D);
  split_transpose<<<dim3(4, HD), blk, 0, stream>>>(Wg2, Wg2h, Wg2l, HD, HD, HD);

  // ---- MLP layer 1 ----
  gemm_mfma_split<<<dim3(D / 128, rb), blk, 0, stream>>>(xh, xl, W1h, W1l, b1, hA, n, D, Fp);
  hipMemsetAsync(ssum, 0, 2048 * sizeof(float), stream);
  bn_stats<<<dim3(64, D / 256), blk, 0, stream>>>(hA, n, D, ssum, ssq);
  bn_apply_elu_split<<<1024, blk, 0, stream>>>(hA, n, D, ssum, ssq, g1, be1, hsph, hspl);

  // ---- MLP layer 2 ----
  gemm_mfma_split<<<dim3(D / 128, rb), blk, 0, stream>>>(hsph, hspl, W2h, W2l, b2, hB, n, D, D);
  hipMemsetAsync(ssum, 0, 2048 * sizeof(float), stream);
  bn_stats<<<dim3(64, D / 256), blk, 0, stream>>>(hB, n, D, ssum, ssq);
  bn_apply_elu_split<<<1024, blk, 0, stream>>>(hB, n, D, ssum, ssq, g2, be2, hsph, hspl);

  // ---- MLP layer 3 ----
  gemm_mfma_split<<<dim3(D / 128, rb), blk, 0, stream>>>(hsph, hspl, W3h, W3l, b3, hA, n, D, D);
  hipMemsetAsync(ssum, 0, 2048 * sizeof(float), stream);
  bn_stats<<<dim3(64, D / 256), blk, 0, stream>>>(hA, n, D, ssum, ssq);
  bn_apply_elu_split<<<1024, blk, 0, stream>>>(hA, n, D, ssum, ssq, g3, be3, hsph, hspl);

  // ---- GAT layer 1 ----
  gemm_mfma_split<<<dim3(HD / 128, rb), blk, 0, stream>>>(hsph, hspl, Wg1h, Wg1l, nullptr, hg, n, HD, D);
  att_scores<<<n, blk, 0, stream>>>(hg, as1, ad1, asrc, adst, n);
  hipMemsetAsync(denom, 0, n * 4 * sizeof(float), stream);
  edge_denom<<<eb, blk, 0, stream>>>(srcA, dstA, asrc, adst, expe, denom, n, E0, E);
  aggregate_csr<<<n, blk, 0, stream>>>(hg, row_start, csr_src, csr_eid, expe, denom, bg1, agg);

  // ---- BN4 + ELU (emits split for gat2's GEMM) ----
  hipMemsetAsync(ssum, 0, 2048 * sizeof(float), stream);
  bn_stats<<<dim3(64, HD / 256), blk, 0, stream>>>(agg, n, HD, ssum, ssq);
  bn_apply_elu_split<<<2048, blk, 0, stream>>>(agg, n, HD, ssum, ssq, g4, be4, hsph, hspl);

  // ---- GAT layer 2 (writes d_out) ----
  gemm_mfma_split<<<dim3(HD / 128, rb), blk, 0, stream>>>(hsph, hspl, Wg2h, Wg2l, nullptr, hg, n, HD, HD);
  att_scores<<<n, blk, 0, stream>>>(hg, as2, ad2, asrc, adst, n);
  hipMemsetAsync(denom, 0, n * 4 * sizeof(float), stream);
  edge_denom<<<eb, blk, 0, stream>>>(srcA, dstA, asrc, adst, expe, denom, n, E0, E);
  aggregate_csr<<<n, blk, 0, stream>>>(hg, row_start, csr_src, csr_eid, expe, denom, bg2, out);
}

// Round 4
// 869.407 us; speedup vs baseline: 2.8364x; 1.0568x over previous
//
#include <hip/hip_runtime.h>
#include <hip/hip_bf16.h>

typedef __attribute__((ext_vector_type(8))) short short8v;
typedef __attribute__((ext_vector_type(4))) float f32x4;

// ===== MFMA GEMM, fp32 A split in-kernel, pre-split B^T, optional split-K ====
// C[M,N] = A[M,K](fp32) @ B[N,Kp]^T (bf16 hi/lo).  3-term split:
// C = Ah*Bh + Ah*Bl + Al*Bh  (rel err ~2^-17).
// gridDim.z = Z: if Z==1 write C directly (+bias), else write partials
// out[z][M][N] (reduce_bias sums them).
template <bool AL4>
__global__ __launch_bounds__(256) void gemm_a32(
    const float* __restrict__ A, const __hip_bfloat16* __restrict__ Bh,
    const __hip_bfloat16* __restrict__ Bl, float* __restrict__ out,
    const float* __restrict__ bias, int M, int N, int K, int Kp) {
  __shared__ ushort Ash[128][40];
  __shared__ ushort Asl[128][40];
  __shared__ ushort Bsh[128][40];
  __shared__ ushort Bsl[128][40];
  const int tid = threadIdx.x;
  const int lane = tid & 63;
  const int w = tid >> 6, wr = w >> 1, wc = w & 1;
  const int brow = blockIdx.y * 128, bcol = blockIdx.x * 128;
  const int l15 = lane & 15, koff = (lane >> 4) * 8;
  const int arow = tid >> 1, aseg = (tid & 1) * 16;  // 128 rows x 32 k per tile
  const int Zn = gridDim.z, z = blockIdx.z;
  const int nK = (K + 31) >> 5;
  const int ks0 = (int)(((long)nK * z) / Zn);
  const int ks1 = (int)(((long)nK * (z + 1)) / Zn);

  f32x4 acc[4][4] = {};

  for (int ks = ks0; ks < ks1; ++ks) {
    const int k0 = ks << 5;
    // ---- A: 16 fp32 per thread -> bf16 hi/lo ----
    const int ar = brow + arow;
    float av[16];
    if (ar < M) {
      if (AL4) {
        const float4* ap = (const float4*)(A + (long)ar * K + k0 + aseg);
#pragma unroll
        for (int q = 0; q < 4; ++q) {
          float4 f = ap[q];
          av[q * 4 + 0] = f.x;
          av[q * 4 + 1] = f.y;
          av[q * 4 + 2] = f.z;
          av[q * 4 + 3] = f.w;
        }
      } else {
        const float* aprow = A + (long)ar * K + k0 + aseg;
        if (k0 + aseg + 16 <= K) {
#pragma unroll
          for (int j = 0; j < 16; ++j) av[j] = aprow[j];
        } else {
#pragma unroll
          for (int j = 0; j < 16; ++j)
            av[j] = (k0 + aseg + j < K) ? aprow[j] : 0.f;
        }
      }
    } else {
#pragma unroll
      for (int j = 0; j < 16; ++j) av[j] = 0.f;
    }
    short8v ah0{}, ah1{}, al0{}, al1{};
#pragma unroll
    for (int j = 0; j < 8; ++j) {
      {
        float v = av[j];
        __hip_bfloat16 h = __float2bfloat16(v);
        __hip_bfloat16 l = __float2bfloat16(v - __bfloat162float(h));
        ah0[j] = *(short*)&h;
        al0[j] = *(short*)&l;
      }
      {
        float v = av[j + 8];
        __hip_bfloat16 h = __float2bfloat16(v);
        __hip_bfloat16 l = __float2bfloat16(v - __bfloat162float(h));
        ah1[j] = *(short*)&h;
        al1[j] = *(short*)&l;
      }
    }
    // ---- B: pre-split bf16, 32 shorts per thread per operand ----
    const long boff = (long)(bcol + arow) * Kp + k0 + aseg;
    short8v bh0 = *(const short8v*)(Bh + boff);
    short8v bh1 = *(const short8v*)(Bh + boff + 8);
    short8v bl0 = *(const short8v*)(Bl + boff);
    short8v bl1 = *(const short8v*)(Bl + boff + 8);
    __syncthreads();  // previous iter's LDS reads done
    *(short8v*)&Ash[arow][aseg] = ah0;
    *(short8v*)&Ash[arow][aseg + 8] = ah1;
    *(short8v*)&Asl[arow][aseg] = al0;
    *(short8v*)&Asl[arow][aseg + 8] = al1;
    *(short8v*)&Bsh[arow][aseg] = bh0;
    *(short8v*)&Bsh[arow][aseg + 8] = bh1;
    *(short8v*)&Bsl[arow][aseg] = bl0;
    *(short8v*)&Bsl[arow][aseg + 8] = bl1;
    __syncthreads();

    short8v bfh[4], bfl[4];
#pragma unroll
    for (int nn = 0; nn < 4; ++nn) {
      bfh[nn] = *(const short8v*)&Bsh[wc * 64 + nn * 16 + l15][koff];
      bfl[nn] = *(const short8v*)&Bsl[wc * 64 + nn * 16 + l15][koff];
    }
#pragma unroll
    for (int m = 0; m < 4; ++m) {
      short8v afh = *(const short8v*)&Ash[wr * 64 + m * 16 + l15][koff];
      short8v afl = *(const short8v*)&Asl[wr * 64 + m * 16 + l15][koff];
#pragma unroll
      for (int nn = 0; nn < 4; ++nn) {
        acc[m][nn] = __builtin_amdgcn_mfma_f32_16x16x32_bf16(afh, bfh[nn], acc[m][nn], 0, 0, 0);
        acc[m][nn] = __builtin_amdgcn_mfma_f32_16x16x32_bf16(afh, bfl[nn], acc[m][nn], 0, 0, 0);
        acc[m][nn] = __builtin_amdgcn_mfma_f32_16x16x32_bf16(afl, bfh[nn], acc[m][nn], 0, 0, 0);
      }
    }
  }

  const bool direct = (Zn == 1);
  float* outp = direct ? out : out + (long)z * M * N;
#pragma unroll
  for (int m = 0; m < 4; ++m) {
#pragma unroll
    for (int nn = 0; nn < 4; ++nn) {
      int col = bcol + wc * 64 + nn * 16 + l15;
      float bv = (direct && bias) ? bias[col] : 0.f;
#pragma unroll
      for (int r = 0; r < 4; ++r) {
        int row = brow + wr * 64 + m * 16 + (lane >> 4) * 4 + r;
        if (row < M) outp[(long)row * N + col] = acc[m][nn][r] + bv;
      }
    }
  }
}

// ===== split-K reduction: C = sum_z P[z] + bias ==============================
__global__ __launch_bounds__(256) void reduce_bias(
    const float* __restrict__ P, const float* __restrict__ bias,
    float* __restrict__ C, long MN, int N, int Z) {
  for (long i = blockIdx.x * (long)blockDim.x + threadIdx.x; i < MN;
       i += (long)gridDim.x * blockDim.x) {
    float s = bias[(int)(i % N)];
    for (int zz = 0; zz < Z; ++zz) s += P[(long)zz * MN + i];
    C[i] = s;
  }
}

// ===== tiled transpose + bf16 hi/lo split: W[K][N] -> Oh/Ol [N][Kp] ==========
__global__ __launch_bounds__(256) void trans_split(
    const float* __restrict__ W, __hip_bfloat16* __restrict__ Oh,
    __hip_bfloat16* __restrict__ Ol, int K, int N, int Kp) {
  __shared__ float tile[64][65];
  const int k0 = blockIdx.x * 64, n0 = blockIdx.y * 64;
  const int tx = threadIdx.x & 63, ty = threadIdx.x >> 6;  // ty in [0,4)
#pragma unroll
  for (int j = 0; j < 16; ++j) {
    int r = ty * 16 + j;
    int k = k0 + r;
    tile[r][tx] = (k < K) ? W[(long)k * N + n0 + tx] : 0.f;
  }
  __syncthreads();
#pragma unroll
  for (int j = 0; j < 16; ++j) {
    int a = ty * 16 + j;  // n within tile
    float v = tile[tx][a];
    __hip_bfloat16 h = __float2bfloat16(v);
    __hip_bfloat16 l = __float2bfloat16(v - __bfloat162float(h));
    long o = (long)(n0 + a) * Kp + k0 + tx;
    Oh[o] = h;
    Ol[o] = l;
  }
}

// ===== BatchNorm stats =======================================================
__global__ __launch_bounds__(256) void bn_stats(
    const float* __restrict__ h, int M, int N,
    float* __restrict__ sum, float* __restrict__ sumsq) {
  int col = blockIdx.y * 256 + threadIdx.x;
  float s = 0.f, sq = 0.f;
  for (int r = blockIdx.x; r < M; r += gridDim.x) {
    float v = h[(long)r * N + col];
    s += v;
    sq += v * v;
  }
  atomicAdd(&sum[col], s);
  atomicAdd(&sumsq[col], sq);
}

// ===== BN apply + ELU (in place, fp32) =======================================
__global__ __launch_bounds__(256) void bn_apply_elu(
    float* __restrict__ h, int M, int N,
    const float* __restrict__ sum, const float* __restrict__ sumsq,
    const float* __restrict__ g, const float* __restrict__ be) {
  long total = (long)M * N;
  float invM = 1.f / (float)M;
  for (long i = blockIdx.x * (long)blockDim.x + threadIdx.x; i < total;
       i += (long)gridDim.x * blockDim.x) {
    int col = (int)(i % N);
    float mean = sum[col] * invM;
    float var = sumsq[col] * invM - mean * mean;
    float v = (h[i] - mean) * rsqrtf(var + 1e-5f) * g[col] + be[col];
    h[i] = v > 0.f ? v : expm1f(v);
  }
}

// ===== GAT attention scores ==================================================
__global__ __launch_bounds__(256) void att_scores(
    const float* __restrict__ hg, const float* __restrict__ att_s,
    const float* __restrict__ att_d, float* __restrict__ a_src,
    float* __restrict__ a_dst, int n) {
  int node = blockIdx.x;
  int head = threadIdx.x >> 6;
  int lane = threadIdx.x & 63;
  const float* row = hg + (long)node * 1024 + head * 256;
  const float* as = att_s + head * 256;
  const float* ad = att_d + head * 256;
  float ss = 0.f, sd = 0.f;
#pragma unroll
  for (int d = lane; d < 256; d += 64) {
    float v = row[d];
    ss += v * as[d];
    sd += v * ad[d];
  }
#pragma unroll
  for (int off = 32; off; off >>= 1) {
    ss += __shfl_down(ss, off);
    sd += __shfl_down(sd, off);
  }
  if (lane == 0) {
    a_src[node * 4 + head] = ss;
    a_dst[node * 4 + head] = sd;
  }
}

// ===== edge softmax: exp(e) and per-dst denominator ==========================
__global__ __launch_bounds__(256) void edge_denom(
    const int* __restrict__ srcA, const int* __restrict__ dstA,
    const float* __restrict__ a_src, const float* __restrict__ a_dst,
    float* __restrict__ expe, float* __restrict__ denom, int n, int E0, int E) {
  int e = blockIdx.x * blockDim.x + threadIdx.x;
  if (e >= E) return;
  int s, d;
  if (e < E0) {
    s = srcA[e];
    d = dstA[e];
    if (s == d) d = (d + 1) % n;
  } else {
    s = d = e - E0;
  }
#pragma unroll
  for (int h = 0; h < 4; ++h) {
    float v = a_src[s * 4 + h] + a_dst[d * 4 + h];
    v = v > 0.f ? v : 0.2f * v;
    float ex = expf(v);
    expe[e * 4 + h] = ex;
    atomicAdd(&denom[d * 4 + h], ex);
  }
}

// ===== CSR build =============================================================
__global__ __launch_bounds__(256) void deg_count(
    const int* __restrict__ srcA, const int* __restrict__ dstA,
    int* __restrict__ deg, int n, int E0, int E) {
  int e = blockIdx.x * blockDim.x + threadIdx.x;
  if (e >= E) return;
  int d;
  if (e < E0) {
    int s = srcA[e];
    d = dstA[e];
    if (s == d) d = (d + 1) % n;
  } else {
    d = e - E0;
  }
  atomicAdd(&deg[d], 1);
}

__global__ __launch_bounds__(256) void scan_rows(
    const int* __restrict__ deg, int* __restrict__ row_start, int n) {
  __shared__ int sums[256];
  int t = threadIdx.x;
  int chunk = (n + 255) / 256;
  int start = t * chunk, end = min(start + chunk, n);
  int s = 0;
  for (int i = start; i < end; ++i) s += deg[i];
  sums[t] = s;
  __syncthreads();
  for (int off = 1; off < 256; off <<= 1) {
    int v = (t >= off) ? sums[t - off] : 0;
    __syncthreads();
    sums[t] += v;
    __syncthreads();
  }
  int run = (t == 0) ? 0 : sums[t - 1];
  for (int i = start; i < end; ++i) {
    row_start[i] = run;
    run += deg[i];
  }
  if (t == 255) row_start[n] = run;
}

__global__ __launch_bounds__(256) void scatter_edges(
    const int* __restrict__ srcA, const int* __restrict__ dstA,
    int* __restrict__ cursor, int* __restrict__ csr_src,
    int* __restrict__ csr_eid, int n, int E0, int E) {
  int e = blockIdx.x * blockDim.x + threadIdx.x;
  if (e >= E) return;
  int s, d;
  if (e < E0) {
    s = srcA[e];
    d = dstA[e];
    if (s == d) d = (d + 1) % n;
  } else {
    s = d = e - E0;
  }
  int pos = atomicAdd(&cursor[d], 1);
  csr_src[pos] = s;
  csr_eid[pos] = e;
}

// ===== gather aggregation: one block per dst node ============================
__global__ __launch_bounds__(256) void aggregate_csr(
    const float* __restrict__ hg, const int* __restrict__ row_start,
    const int* __restrict__ csr_src, const int* __restrict__ csr_eid,
    const float* __restrict__ expe, const float* __restrict__ denom,
    const float* __restrict__ bias, float* __restrict__ out) {
  int d = blockIdx.x;
  int t = threadIdx.x;
  int p0 = row_start[d], p1 = row_start[d + 1];
  float rden[4], acc[4];
#pragma unroll
  for (int h = 0; h < 4; ++h) {
    rden[h] = 1.f / (denom[d * 4 + h] + 1e-16f);
    acc[h] = bias[h * 256 + t];
  }
  for (int p = p0; p < p1; ++p) {
    int s = csr_src[p];
    int e = csr_eid[p];
#pragma unroll
    for (int h = 0; h < 4; ++h) {
      float a = expe[e * 4 + h] * rden[h];
      acc[h] += hg[(long)s * 1024 + h * 256 + t] * a;
    }
  }
#pragma unroll
  for (int h = 0; h < 4; ++h) out[(long)d * 1024 + h * 256 + t] = acc[h];
}

extern "C" void kernel_launch(void* const* d_in, const int* in_sizes, int n_in,
                              void* d_out, int out_size, void* d_ws,
                              size_t ws_size, hipStream_t stream) {
  const float* x = (const float*)d_in[0];
  const int* edges = (const int*)d_in[1];
  const float* W1 = (const float*)d_in[2];
  const float* b1 = (const float*)d_in[3];
  const float* W2 = (const float*)d_in[4];
  const float* b2 = (const float*)d_in[5];
  const float* W3 = (const float*)d_in[6];
  const float* b3 = (const float*)d_in[7];
  const float* g1 = (const float*)d_in[8];
  const float* be1 = (const float*)d_in[9];
  const float* g2 = (const float*)d_in[10];
  const float* be2 = (const float*)d_in[11];
  const float* g3 = (const float*)d_in[12];
  const float* be3 = (const float*)d_in[13];
  const float* g4 = (const float*)d_in[14];
  const float* be4 = (const float*)d_in[15];
  const float* Wg1 = (const float*)d_in[16];
  const float* as1 = (const float*)d_in[17];
  const float* ad1 = (const float*)d_in[18];
  const float* bg1 = (const float*)d_in[19];
  const float* Wg2 = (const float*)d_in[20];
  const float* as2 = (const float*)d_in[21];
  const float* ad2 = (const float*)d_in[22];
  const float* bg2 = (const float*)d_in[23];
  float* out = (float*)d_out;

  const int n = 10000, E0 = 160000, E = 170000;
  const int F = 2613, Fp = 2624, D = 256, HD = 1024;
  const int* srcA = edges;
  const int* dstA = edges + E0;

  // ---- workspace layout ----
  uint8_t* p = (uint8_t*)d_ws;
  auto alloc = [&](size_t bytes) -> void* {
    void* r = (void*)p;
    p += (bytes + 255) & ~(size_t)255;
    return r;
  };
  float* hA = (float*)alloc((size_t)n * D * 4);
  float* hB = (float*)alloc((size_t)n * D * 4);
  float* hg = (float*)alloc((size_t)n * HD * 4);
  float* agg = (float*)alloc((size_t)n * HD * 4);
  float* pbuf = (float*)alloc((size_t)4 * n * D * 4);  // split-K partials
  __hip_bfloat16* W1h = (__hip_bfloat16*)alloc((size_t)D * Fp * 2);
  __hip_bfloat16* W1l = (__hip_bfloat16*)alloc((size_t)D * Fp * 2);
  __hip_bfloat16* W2h = (__hip_bfloat16*)alloc((size_t)D * D * 2);
  __hip_bfloat16* W2l = (__hip_bfloat16*)alloc((size_t)D * D * 2);
  __hip_bfloat16* W3h = (__hip_bfloat16*)alloc((size_t)D * D * 2);
  __hip_bfloat16* W3l = (__hip_bfloat16*)alloc((size_t)D * D * 2);
  __hip_bfloat16* Wg1h = (__hip_bfloat16*)alloc((size_t)HD * D * 2);
  __hip_bfloat16* Wg1l = (__hip_bfloat16*)alloc((size_t)HD * D * 2);
  __hip_bfloat16* Wg2h = (__hip_bfloat16*)alloc((size_t)HD * HD * 2);
  __hip_bfloat16* Wg2l = (__hip_bfloat16*)alloc((size_t)HD * HD * 2);
  float* asrc = (float*)alloc((size_t)n * 4 * 4);
  float* adst = (float*)alloc((size_t)n * 4 * 4);
  float* denom = (float*)alloc((size_t)n * 4 * 4);
  float* expe = (float*)alloc((size_t)E * 4 * 4);
  float* ssum = (float*)alloc(1024 * 4);
  float* ssq = (float*)alloc(1024 * 4);
  int* deg = (int*)alloc((size_t)n * 4);
  int* row_start = (int*)alloc((size_t)(n + 1) * 4);
  int* cursor = (int*)alloc((size_t)n * 4);
  int* csr_src = (int*)alloc((size_t)E * 4);
  int* csr_eid = (int*)alloc((size_t)E * 4);

  dim3 blk(256);
  const int rb = (n + 127) / 128;  // 79 row blocks
  const int eb = (E + 255) / 256;
  const long MND = (long)n * D;

  // ---- CSR build (edges only; reused by both GAT layers) ----
  hipMemsetAsync(deg, 0, n * sizeof(int), stream);
  deg_count<<<eb, blk, 0, stream>>>(srcA, dstA, deg, n, E0, E);
  scan_rows<<<1, blk, 0, stream>>>(deg, row_start, n);
  hipMemcpyAsync(cursor, row_start, n * sizeof(int), hipMemcpyDeviceToDevice, stream);
  scatter_edges<<<eb, blk, 0, stream>>>(srcA, dstA, cursor, csr_src, csr_eid, n, E0, E);

  // ---- weight transpose+split (coalesced, tiled) ----
  trans_split<<<dim3(Fp / 64, D / 64), blk, 0, stream>>>(W1, W1h, W1l, F, D, Fp);
  trans_split<<<dim3(D / 64, D / 64), blk, 0, stream>>>(W2, W2h, W2l, D, D, D);
  trans_split<<<dim3(D / 64, D / 64), blk, 0, stream>>>(W3, W3h, W3l, D, D, D);
  trans_split<<<dim3(D / 64, HD / 64), blk, 0, stream>>>(Wg1, Wg1h, Wg1l, D, HD, D);
  trans_split<<<dim3(HD / 64, HD / 64), blk, 0, stream>>>(Wg2, Wg2h, Wg2l, HD, HD, HD);

  // ---- MLP layer 1: hA = elu(bn(x@W1+b1))  [split-K=4] ----
  gemm_a32<false><<<dim3(D / 128, rb, 4), blk, 0, stream>>>(x, W1h, W1l, pbuf, nullptr, n, D, F, Fp);
  reduce_bias<<<2048, blk, 0, stream>>>(pbuf, b1, hA, MND, D, 4);
  hipMemsetAsync(ssum, 0, 2048 * sizeof(float), stream);
  bn_stats<<<dim3(64, D / 256), blk, 0, stream>>>(hA, n, D, ssum, ssq);
  bn_apply_elu<<<1024, blk, 0, stream>>>(hA, n, D, ssum, ssq, g1, be1);

  // ---- MLP layer 2: hB = elu(bn(hA@W2+b2))  [split-K=2] ----
  gemm_a32<true><<<dim3(D / 128, rb, 2), blk, 0, stream>>>(hA, W2h, W2l, pbuf, nullptr, n, D, D, D);
  reduce_bias<<<2048, blk, 0, stream>>>(pbuf, b2, hB, MND, D, 2);
  hipMemsetAsync(ssum, 0, 2048 * sizeof(float), stream);
  bn_stats<<<dim3(64, D / 256), blk, 0, stream>>>(hB, n, D, ssum, ssq);
  bn_apply_elu<<<1024, blk, 0, stream>>>(hB, n, D, ssum, ssq, g2, be2);

  // ---- MLP layer 3: hA = elu(bn(hB@W3+b3))  [split-K=2] ----
  gemm_a32<true><<<dim3(D / 128, rb, 2), blk, 0, stream>>>(hB, W3h, W3l, pbuf, nullptr, n, D, D, D);
  reduce_bias<<<2048, blk, 0, stream>>>(pbuf, b3, hA, MND, D, 2);
  hipMemsetAsync(ssum, 0, 2048 * sizeof(float), stream);
  bn_stats<<<dim3(64, D / 256), blk, 0, stream>>>(hA, n, D, ssum, ssq);
  bn_apply_elu<<<1024, blk, 0, stream>>>(hA, n, D, ssum, ssq, g3, be3);

  // ---- GAT layer 1 ----
  gemm_a32<true><<<dim3(HD / 128, rb, 1), blk, 0, stream>>>(hA, Wg1h, Wg1l, hg, nullptr, n, HD, D, D);
  att_scores<<<n, blk, 0, stream>>>(hg, as1, ad1, asrc, adst, n);
  hipMemsetAsync(denom, 0, n * 4 * sizeof(float), stream);
  edge_denom<<<eb, blk, 0, stream>>>(srcA, dstA, asrc, adst, expe, denom, n, E0, E);
  aggregate_csr<<<n, blk, 0, stream>>>(hg, row_start, csr_src, csr_eid, expe, denom, bg1, agg);

  // ---- BN4 + ELU ----
  hipMemsetAsync(ssum, 0, 2048 * sizeof(float), stream);
  bn_stats<<<dim3(64, HD / 256), blk, 0, stream>>>(agg, n, HD, ssum, ssq);
  bn_apply_elu<<<2048, blk, 0, stream>>>(agg, n, HD, ssum, ssq, g4, be4);

  // ---- GAT layer 2 (writes d_out) ----
  gemm_a32<true><<<dim3(HD / 128, rb, 1), blk, 0, stream>>>(agg, Wg2h, Wg2l, hg, nullptr, n, HD, HD, HD);
  att_scores<<<n, blk, 0, stream>>>(hg, as2, ad2, asrc, adst, n);
  hipMemsetAsync(denom, 0, n * 4 * sizeof(float), stream);
  edge_denom<<<eb, blk, 0, stream>>>(srcA, dstA, asrc, adst, expe, denom, n, E0, E);
  aggregate_csr<<<n, blk, 0, stream>>>(hg, row_start, csr_src, csr_eid, expe, denom, bg2, out);
}